// Round 2
// baseline (99.672 us; speedup 1.0000x reference)
//
#include <hip/hip_runtime.h>
#include <hip/hip_bf16.h>

// NT-Xent loss, MI355X. B=4096, D=256, N=8192, temp=0.5.
// normalize -> bf16 zn -> MFMA Gram with fused exp/LSE partials -> finalize.
// gram: block = 256 i-rows x 512 j-cols, 4 waves x 64 rows, A in registers
// (a[4][8] = 128 VGPR -> 64 FLOP per LDS byte), B staged via global_load_lds
// (pre-swizzled global source, linear LDS dest), double-buffered.

typedef __attribute__((ext_vector_type(4))) float f32x4;
typedef __attribute__((ext_vector_type(8))) short s16x8;

#define N_TOT 8192
#define B_HALF 4096
#define D_DIM 256
#define JSPLIT 16
#define JCOLS 512
#define NSTEP 8
#define LOG2E2 2.8853900817779268f  // 2/T * log2(e) folded: exp(sim) = exp2(dot*LOG2E2)

__device__ inline unsigned short f2bf(float f) {
  __hip_bfloat16 h = __float2bfloat16(f);
  return *reinterpret_cast<unsigned short*>(&h);
}

__global__ __launch_bounds__(256) void nrm_kernel(const float* __restrict__ z1,
                                                  const float* __restrict__ z2,
                                                  unsigned short* __restrict__ zn) {
  int row = blockIdx.x * 4 + (threadIdx.x >> 6);
  int lane = threadIdx.x & 63;
  const float* src = (row < B_HALF) ? (z1 + (size_t)row * D_DIM)
                                    : (z2 + (size_t)(row - B_HALF) * D_DIM);
  f32x4 v = *reinterpret_cast<const f32x4*>(src + lane * 4);
  float ss = v.x * v.x + v.y * v.y + v.z * v.z + v.w * v.w;
#pragma unroll
  for (int m = 32; m >= 1; m >>= 1) ss += __shfl_xor(ss, m);
  float inv = 1.0f / fmaxf(sqrtf(ss), 1e-8f);
  ushort4 o;
  o.x = f2bf(v.x * inv);
  o.y = f2bf(v.y * inv);
  o.z = f2bf(v.z * inv);
  o.w = f2bf(v.w * inv);
  *reinterpret_cast<ushort4*>(zn + (size_t)row * D_DIM + lane * 4) = o;
}

__global__ __launch_bounds__(256, 2) void gram_kernel(const unsigned short* __restrict__ zn,
                                                      float* __restrict__ psum,
                                                      float* __restrict__ ppos) {
  __shared__ __align__(16) char bt[2 * 64 * 512];  // double-buffered 64-row B tiles
  const int tid = threadIdx.x;
  const int w = tid >> 6, l = tid & 63;
  const int lm = l & 15, hh = l >> 4;
  const int ibase = blockIdx.x * 256;
  const int r0w = ibase + w * 64;              // this wave's 64 i-rows
  const int jbase = blockIdx.y * JCOLS;
  const char* znb = reinterpret_cast<const char*>(zn);

  // stage step s (64 B-rows) into buffer bi. LDS dest linear (lane*16);
  // swizzle realized by XOR-permuting the global source within each 512B row.
  auto stage = [&](int s, int bi) {
    const char* gs = znb + (size_t)(jbase + s * 64) * 512;
    char* ldsbase = bt + bi * 32768 + (w * 16) * 512;
#pragma unroll
    for (int q = 0; q < 8; ++q) {
      int rloc = w * 16 + q * 2 + (l >> 5);
      const char* g = gs + (size_t)rloc * 512 + (((l & 31) * 16) ^ ((rloc & 7) << 4));
      __builtin_amdgcn_global_load_lds(
          (const __attribute__((address_space(1))) void*)g,
          (__attribute__((address_space(3))) void*)(ldsbase + q * 1024), 16, 0, 0);
    }
  };

  stage(0, 0);  // prefetch first tile; overlaps the A-fragment loads below

  // A fragments: 64 rows x K=256 in registers. lane: row lm (+rf*16), k-bytes
  // g*64 + hh*16 .. +15 (8 bf16). Same layout as B frags (Gram symmetry).
  s16x8 a[4][8];
#pragma unroll
  for (int rf = 0; rf < 4; ++rf)
#pragma unroll
    for (int g = 0; g < 8; ++g)
      a[rf][g] = *reinterpret_cast<const s16x8*>(
          znb + (size_t)(r0w + rf * 16 + lm) * 512 + g * 64 + hh * 16);

  float sume[4][4];
#pragma unroll
  for (int rf = 0; rf < 4; ++rf)
#pragma unroll
    for (int t = 0; t < 4; ++t) sume[rf][t] = 0.f;

  const int swz = (lm & 7) << 4;

#pragma unroll 2
  for (int s = 0; s < NSTEP; ++s) {
    __syncthreads();  // drains my stage loads (vmcnt0) + all waves done w/ prev buf
    if (s + 1 < NSTEP) stage(s + 1, (s + 1) & 1);  // async prefetch under compute
    const char* bp = bt + (s & 1) * 32768;

#pragma unroll
    for (int jt = 0; jt < 4; ++jt) {
      const char* br = bp + (jt * 16 + lm) * 512;
      f32x4 ac[4];
#pragma unroll
      for (int rf = 0; rf < 4; ++rf) ac[rf] = (f32x4){0.f, 0.f, 0.f, 0.f};
#pragma unroll
      for (int g = 0; g < 8; ++g) {
        s16x8 bf = *reinterpret_cast<const s16x8*>(br + ((g * 64 + hh * 16) ^ swz));
        ac[0] = __builtin_amdgcn_mfma_f32_16x16x32_bf16(a[0][g], bf, ac[0], 0, 0, 0);
        ac[1] = __builtin_amdgcn_mfma_f32_16x16x32_bf16(a[1][g], bf, ac[1], 0, 0, 0);
        ac[2] = __builtin_amdgcn_mfma_f32_16x16x32_bf16(a[2][g], bf, ac[2], 0, 0, 0);
        ac[3] = __builtin_amdgcn_mfma_f32_16x16x32_bf16(a[3][g], bf, ac[3], 0, 0, 0);
      }
      const int jtb = jbase + s * 64 + jt * 16;
#pragma unroll
      for (int rf = 0; rf < 4; ++rf) {
        const int itb = r0w + rf * 16;
        const bool dg = (itb == jtb);
        const bool ps = ((itb ^ B_HALF) == jtb);
        if (dg | ps) {  // wave-uniform; at most 8 of 128 tiles per wave
#pragma unroll
          for (int t = 0; t < 4; ++t) {
            float sv = ac[rf][t];
            float e = exp2f(sv * LOG2E2);
            bool self = (lm == hh * 4 + t);  // C/D map: row=hh*4+t, col=lm
            if (dg && self) e = 0.f;         // mask diagonal
            sume[rf][t] += e;
            if (ps && self) ppos[itb + hh * 4 + t] = sv * 2.0f;  // unique writer
          }
        } else {
#pragma unroll
          for (int t = 0; t < 4; ++t) sume[rf][t] += exp2f(ac[rf][t] * LOG2E2);
        }
      }
    }
  }

  // reduce partial sums across the 16 lanes (lm) sharing each row
#pragma unroll
  for (int rf = 0; rf < 4; ++rf)
#pragma unroll
    for (int t = 0; t < 4; ++t) {
      float v = sume[rf][t];
#pragma unroll
      for (int m = 1; m < 16; m <<= 1) v += __shfl_xor(v, m);
      if (lm == 0) psum[(size_t)blockIdx.y * N_TOT + r0w + rf * 16 + hh * 4 + t] = v;
    }
}

__global__ __launch_bounds__(256) void fin1_kernel(const float* __restrict__ psum,
                                                   const float* __restrict__ ppos,
                                                   float* __restrict__ partial) {
  int i = blockIdx.x * 256 + threadIdx.x;
  float se = 0.f;
#pragma unroll
  for (int s = 0; s < JSPLIT; ++s) se += psum[(size_t)s * N_TOT + i];
  float acc = logf(se) - ppos[i];
#pragma unroll
  for (int m = 32; m >= 1; m >>= 1) acc += __shfl_xor(acc, m);
  __shared__ float red[4];
  if ((threadIdx.x & 63) == 0) red[threadIdx.x >> 6] = acc;
  __syncthreads();
  if (threadIdx.x == 0) partial[blockIdx.x] = red[0] + red[1] + red[2] + red[3];
}

__global__ void fin2_kernel(const float* __restrict__ partial, float* __restrict__ out) {
  float v = (threadIdx.x < 32) ? partial[threadIdx.x] : 0.f;
#pragma unroll
  for (int m = 32; m >= 1; m >>= 1) v += __shfl_xor(v, m);
  if (threadIdx.x == 0) out[0] = v / (float)N_TOT;
}

extern "C" void kernel_launch(void* const* d_in, const int* in_sizes, int n_in,
                              void* d_out, int out_size, void* d_ws, size_t ws_size,
                              hipStream_t stream) {
  const float* z1 = (const float*)d_in[0];
  const float* z2 = (const float*)d_in[1];
  float* out = (float*)d_out;
  char* ws = (char*)d_ws;

  unsigned short* zn = (unsigned short*)ws;                 // 4 MiB
  float* psum = (float*)(ws + (size_t)N_TOT * D_DIM * 2);   // 16*8192 f32 = 512 KiB
  float* ppos = psum + (size_t)JSPLIT * N_TOT;              // 8192 f32
  float* partial = ppos + N_TOT;                            // 32 f32

  nrm_kernel<<<N_TOT / 4, 256, 0, stream>>>(z1, z2, zn);
  gram_kernel<<<dim3(N_TOT / 256, JSPLIT), 256, 0, stream>>>(zn, psum, ppos);
  fin1_kernel<<<N_TOT / 256, 256, 0, stream>>>(psum, ppos, partial);
  fin2_kernel<<<1, 64, 0, stream>>>(partial, out);
}

// Round 3
// 62.738 us; speedup vs baseline: 1.5887x; 1.5887x over previous
//
#include <hip/hip_runtime.h>
#include <hip/hip_bf16.h>

// NT-Xent loss, MI355X. B=4096, D=256, N=8192, temp=0.5.
// normalize -> bf16 zn -> MFMA Gram with fused exp/LSE partials -> finalize.
// gram: block = 256 i-rows x 512 j-cols, 4 waves x 64 rows, A in registers
// (a[4][8] = 128 VGPR -> 64 FLOP per LDS byte), B staged via global_load_lds
// (pre-swizzled global source, linear LDS dest), double-buffered.
// R3 fix: NO min-waves launch bound (R2's (256,2) capped VGPRs at 128 and
// spilled all of A to scratch: WRITE_SIZE 0.5->93MB). Plain (256) lets the
// allocator take the <=256-reg / 2-waves-per-SIMD tier.

typedef __attribute__((ext_vector_type(4))) float f32x4;
typedef __attribute__((ext_vector_type(8))) short s16x8;

#define N_TOT 8192
#define B_HALF 4096
#define D_DIM 256
#define JSPLIT 16
#define JCOLS 512
#define NSTEP 8
#define LOG2E2 2.8853900817779268f  // (1/T)*log2(e): exp(dot/T) = exp2(dot*LOG2E2)

__device__ inline unsigned short f2bf(float f) {
  __hip_bfloat16 h = __float2bfloat16(f);
  return *reinterpret_cast<unsigned short*>(&h);
}

__device__ inline float fexp2(float x) {
#if __has_builtin(__builtin_amdgcn_exp2f)
  return __builtin_amdgcn_exp2f(x);  // raw v_exp_f32; args here are in [-3,3]
#else
  return exp2f(x);
#endif
}

__global__ __launch_bounds__(256) void nrm_kernel(const float* __restrict__ z1,
                                                  const float* __restrict__ z2,
                                                  unsigned short* __restrict__ zn) {
  int row = blockIdx.x * 4 + (threadIdx.x >> 6);
  int lane = threadIdx.x & 63;
  const float* src = (row < B_HALF) ? (z1 + (size_t)row * D_DIM)
                                    : (z2 + (size_t)(row - B_HALF) * D_DIM);
  f32x4 v = *reinterpret_cast<const f32x4*>(src + lane * 4);
  float ss = v.x * v.x + v.y * v.y + v.z * v.z + v.w * v.w;
#pragma unroll
  for (int m = 32; m >= 1; m >>= 1) ss += __shfl_xor(ss, m);
  float inv = 1.0f / fmaxf(sqrtf(ss), 1e-8f);
  ushort4 o;
  o.x = f2bf(v.x * inv);
  o.y = f2bf(v.y * inv);
  o.z = f2bf(v.z * inv);
  o.w = f2bf(v.w * inv);
  *reinterpret_cast<ushort4*>(zn + (size_t)row * D_DIM + lane * 4) = o;
}

__global__ __launch_bounds__(256) void gram_kernel(const unsigned short* __restrict__ zn,
                                                   float* __restrict__ psum,
                                                   float* __restrict__ ppos) {
  __shared__ __align__(16) char bt[2 * 64 * 512];  // double-buffered 64-row B tiles
  const int tid = threadIdx.x;
  const int w = tid >> 6, l = tid & 63;
  const int lm = l & 15, hh = l >> 4;
  const int r0w = blockIdx.x * 256 + w * 64;  // this wave's 64 i-rows
  const int jbase = blockIdx.y * JCOLS;
  const char* znb = reinterpret_cast<const char*>(zn);

  // stage step s (64 B-rows) into buffer bi. LDS dest linear (lane*16);
  // swizzle realized by XOR-permuting the global source within each 512B row.
  auto stage = [&](int s, int bi) {
    const char* gs = znb + (size_t)(jbase + s * 64) * 512;
    char* ldsbase = bt + bi * 32768 + (w * 16) * 512;
#pragma unroll
    for (int q = 0; q < 8; ++q) {
      int rloc = w * 16 + q * 2 + (l >> 5);
      const char* g = gs + (size_t)rloc * 512 + (((l & 31) * 16) ^ ((rloc & 7) << 4));
      __builtin_amdgcn_global_load_lds(
          (const __attribute__((address_space(1))) void*)g,
          (__attribute__((address_space(3))) void*)(ldsbase + q * 1024), 16, 0, 0);
    }
  };

  stage(0, 0);  // prefetch first tile; overlaps the A-fragment loads below

  // A fragments: 64 rows x K=256 in registers. lane: row lm (+rf*16), k-bytes
  // g*64 + hh*16 .. +15 (8 bf16). Same layout as B frags (Gram symmetry).
  s16x8 a[4][8];
#pragma unroll
  for (int rf = 0; rf < 4; ++rf)
#pragma unroll
    for (int g = 0; g < 8; ++g)
      a[rf][g] = *reinterpret_cast<const s16x8*>(
          znb + (size_t)(r0w + rf * 16 + lm) * 512 + g * 64 + hh * 16);

  float sume[4][4];
#pragma unroll
  for (int rf = 0; rf < 4; ++rf)
#pragma unroll
    for (int t = 0; t < 4; ++t) sume[rf][t] = 0.f;

  const int swz = (lm & 7) << 4;

  for (int s = 0; s < NSTEP; ++s) {
    __syncthreads();  // drains my stage loads (vmcnt0) + all waves done w/ prev buf
    if (s + 1 < NSTEP) stage(s + 1, (s + 1) & 1);  // async prefetch under compute
    const char* bp = bt + (s & 1) * 32768;

#pragma unroll
    for (int jt = 0; jt < 4; ++jt) {
      const char* br = bp + (jt * 16 + lm) * 512;
      f32x4 ac[4];
#pragma unroll
      for (int rf = 0; rf < 4; ++rf) ac[rf] = (f32x4){0.f, 0.f, 0.f, 0.f};
#pragma unroll
      for (int g = 0; g < 8; ++g) {
        s16x8 bf = *reinterpret_cast<const s16x8*>(br + ((g * 64 + hh * 16) ^ swz));
        ac[0] = __builtin_amdgcn_mfma_f32_16x16x32_bf16(a[0][g], bf, ac[0], 0, 0, 0);
        ac[1] = __builtin_amdgcn_mfma_f32_16x16x32_bf16(a[1][g], bf, ac[1], 0, 0, 0);
        ac[2] = __builtin_amdgcn_mfma_f32_16x16x32_bf16(a[2][g], bf, ac[2], 0, 0, 0);
        ac[3] = __builtin_amdgcn_mfma_f32_16x16x32_bf16(a[3][g], bf, ac[3], 0, 0, 0);
      }
      const int jtb = jbase + s * 64 + jt * 16;
#pragma unroll
      for (int rf = 0; rf < 4; ++rf) {
        const int itb = r0w + rf * 16;
        const bool dg = (itb == jtb);
        const bool ps = ((itb ^ B_HALF) == jtb);
        if (dg | ps) {  // wave-uniform; at most 8 of 128 tiles per wave
#pragma unroll
          for (int t = 0; t < 4; ++t) {
            float sv = ac[rf][t];
            float e = fexp2(sv * LOG2E2);
            bool self = (lm == hh * 4 + t);  // C/D map: row=hh*4+t, col=lm
            if (dg && self) e = 0.f;         // mask diagonal
            sume[rf][t] += e;
            if (ps && self) ppos[itb + hh * 4 + t] = sv * 2.0f;  // unique writer
          }
        } else {
#pragma unroll
          for (int t = 0; t < 4; ++t) sume[rf][t] += fexp2(ac[rf][t] * LOG2E2);
        }
      }
    }
  }

  // reduce partial sums across the 16 lanes (lm) sharing each row
#pragma unroll
  for (int rf = 0; rf < 4; ++rf)
#pragma unroll
    for (int t = 0; t < 4; ++t) {
      float v = sume[rf][t];
#pragma unroll
      for (int m = 1; m < 16; m <<= 1) v += __shfl_xor(v, m);
      if (lm == 0) psum[(size_t)blockIdx.y * N_TOT + r0w + rf * 16 + hh * 4 + t] = v;
    }
}

__global__ __launch_bounds__(256) void fin1_kernel(const float* __restrict__ psum,
                                                   const float* __restrict__ ppos,
                                                   float* __restrict__ partial) {
  int i = blockIdx.x * 256 + threadIdx.x;
  float se = 0.f;
#pragma unroll
  for (int s = 0; s < JSPLIT; ++s) se += psum[(size_t)s * N_TOT + i];
  float acc = logf(se) - ppos[i];
#pragma unroll
  for (int m = 32; m >= 1; m >>= 1) acc += __shfl_xor(acc, m);
  __shared__ float red[4];
  if ((threadIdx.x & 63) == 0) red[threadIdx.x >> 6] = acc;
  __syncthreads();
  if (threadIdx.x == 0) partial[blockIdx.x] = red[0] + red[1] + red[2] + red[3];
}

__global__ void fin2_kernel(const float* __restrict__ partial, float* __restrict__ out) {
  float v = (threadIdx.x < 32) ? partial[threadIdx.x] : 0.f;
#pragma unroll
  for (int m = 32; m >= 1; m >>= 1) v += __shfl_xor(v, m);
  if (threadIdx.x == 0) out[0] = v / (float)N_TOT;
}

extern "C" void kernel_launch(void* const* d_in, const int* in_sizes, int n_in,
                              void* d_out, int out_size, void* d_ws, size_t ws_size,
                              hipStream_t stream) {
  const float* z1 = (const float*)d_in[0];
  const float* z2 = (const float*)d_in[1];
  float* out = (float*)d_out;
  char* ws = (char*)d_ws;

  unsigned short* zn = (unsigned short*)ws;                 // 4 MiB
  float* psum = (float*)(ws + (size_t)N_TOT * D_DIM * 2);   // 16*8192 f32 = 512 KiB
  float* ppos = psum + (size_t)JSPLIT * N_TOT;              // 8192 f32
  float* partial = ppos + N_TOT;                            // 32 f32

  nrm_kernel<<<N_TOT / 4, 256, 0, stream>>>(z1, z2, zn);
  gram_kernel<<<dim3(N_TOT / 256, JSPLIT), 256, 0, stream>>>(zn, psum, ppos);
  fin1_kernel<<<N_TOT / 256, 256, 0, stream>>>(psum, ppos, partial);
  fin2_kernel<<<1, 64, 0, stream>>>(partial, out);
}

// Round 4
// 52.079 us; speedup vs baseline: 1.9139x; 1.2047x over previous
//
#include <hip/hip_runtime.h>
#include <hip/hip_bf16.h>

// NT-Xent loss, MI355X. B=4096, D=256, N=8192, temp=0.5.
// normalize -> bf16 zn -> MFMA Gram with fused exp/LSE partials -> finalize.
// gram: block = 256 i-rows x 512 j-cols, 4 waves x 64 rows, A in registers
// (a[4][8] = 128 regs -> 64 FLOP per LDS byte), B staged via global_load_lds
// (pre-swizzled global source, linear LDS dest), double-buffered.
// R3: plain (256) -> compiler chose ~264 regs/wave (A in AGPRs) -> 1 wave/SIMD
//     -> latency-bound at 9.7% occupancy, MfmaUtil 24%.
// R4: __launch_bounds__(256,2) -> 256-reg combined budget, live set ~200 fits
//     (R2's spill under the same bound was caused by the since-removed
//     `#pragma unroll 2` on the step loop). Expect 2 waves/SIMD.

typedef __attribute__((ext_vector_type(4))) float f32x4;
typedef __attribute__((ext_vector_type(8))) short s16x8;

#define N_TOT 8192
#define B_HALF 4096
#define D_DIM 256
#define JSPLIT 16
#define JCOLS 512
#define NSTEP 8
#define LOG2E2 2.8853900817779268f  // (1/T)*log2(e): exp(dot/T) = exp2(dot*LOG2E2)

__device__ inline unsigned short f2bf(float f) {
  __hip_bfloat16 h = __float2bfloat16(f);
  return *reinterpret_cast<unsigned short*>(&h);
}

__device__ inline float fexp2(float x) {
#if __has_builtin(__builtin_amdgcn_exp2f)
  return __builtin_amdgcn_exp2f(x);  // raw v_exp_f32; args here are in [-3,3]
#else
  return exp2f(x);
#endif
}

__global__ __launch_bounds__(256) void nrm_kernel(const float* __restrict__ z1,
                                                  const float* __restrict__ z2,
                                                  unsigned short* __restrict__ zn) {
  int row = blockIdx.x * 4 + (threadIdx.x >> 6);
  int lane = threadIdx.x & 63;
  const float* src = (row < B_HALF) ? (z1 + (size_t)row * D_DIM)
                                    : (z2 + (size_t)(row - B_HALF) * D_DIM);
  f32x4 v = *reinterpret_cast<const f32x4*>(src + lane * 4);
  float ss = v.x * v.x + v.y * v.y + v.z * v.z + v.w * v.w;
#pragma unroll
  for (int m = 32; m >= 1; m >>= 1) ss += __shfl_xor(ss, m);
  float inv = 1.0f / fmaxf(sqrtf(ss), 1e-8f);
  ushort4 o;
  o.x = f2bf(v.x * inv);
  o.y = f2bf(v.y * inv);
  o.z = f2bf(v.z * inv);
  o.w = f2bf(v.w * inv);
  *reinterpret_cast<ushort4*>(zn + (size_t)row * D_DIM + lane * 4) = o;
}

__global__ __launch_bounds__(256, 2) void gram_kernel(const unsigned short* __restrict__ zn,
                                                      float* __restrict__ psum,
                                                      float* __restrict__ ppos) {
  __shared__ __align__(16) char bt[2 * 64 * 512];  // double-buffered 64-row B tiles
  const int tid = threadIdx.x;
  const int w = tid >> 6, l = tid & 63;
  const int lm = l & 15, hh = l >> 4;
  const int r0w = blockIdx.x * 256 + w * 64;  // this wave's 64 i-rows
  const int jbase = blockIdx.y * JCOLS;
  const char* znb = reinterpret_cast<const char*>(zn);

  // stage step s (64 B-rows) into buffer bi. LDS dest linear (lane*16);
  // swizzle realized by XOR-permuting the global source within each 512B row.
  auto stage = [&](int s, int bi) {
    const char* gs = znb + (size_t)(jbase + s * 64) * 512;
    char* ldsbase = bt + bi * 32768 + (w * 16) * 512;
#pragma unroll
    for (int q = 0; q < 8; ++q) {
      int rloc = w * 16 + q * 2 + (l >> 5);
      const char* g = gs + (size_t)rloc * 512 + (((l & 31) * 16) ^ ((rloc & 7) << 4));
      __builtin_amdgcn_global_load_lds(
          (const __attribute__((address_space(1))) void*)g,
          (__attribute__((address_space(3))) void*)(ldsbase + q * 1024), 16, 0, 0);
    }
  };

  stage(0, 0);  // prefetch first tile; overlaps the A-fragment loads below

  // A fragments: 64 rows x K=256 in registers. lane: row lm (+rf*16), k-bytes
  // g*64 + hh*16 .. +15 (8 bf16). Same layout as B frags (Gram symmetry).
  s16x8 a[4][8];
#pragma unroll
  for (int rf = 0; rf < 4; ++rf)
#pragma unroll
    for (int g = 0; g < 8; ++g)
      a[rf][g] = *reinterpret_cast<const s16x8*>(
          znb + (size_t)(r0w + rf * 16 + lm) * 512 + g * 64 + hh * 16);

  float sume[4][4];
#pragma unroll
  for (int rf = 0; rf < 4; ++rf)
#pragma unroll
    for (int t = 0; t < 4; ++t) sume[rf][t] = 0.f;

  const int swz = (lm & 7) << 4;

  for (int s = 0; s < NSTEP; ++s) {
    __syncthreads();  // drains my stage loads (vmcnt0) + all waves done w/ prev buf
    if (s + 1 < NSTEP) stage(s + 1, (s + 1) & 1);  // async prefetch under compute
    const char* bp = bt + (s & 1) * 32768;

#pragma unroll
    for (int jt = 0; jt < 4; ++jt) {
      const char* br = bp + (jt * 16 + lm) * 512;
      f32x4 ac[4];
#pragma unroll
      for (int rf = 0; rf < 4; ++rf) ac[rf] = (f32x4){0.f, 0.f, 0.f, 0.f};
#pragma unroll
      for (int g = 0; g < 8; ++g) {
        s16x8 bf = *reinterpret_cast<const s16x8*>(br + ((g * 64 + hh * 16) ^ swz));
        ac[0] = __builtin_amdgcn_mfma_f32_16x16x32_bf16(a[0][g], bf, ac[0], 0, 0, 0);
        ac[1] = __builtin_amdgcn_mfma_f32_16x16x32_bf16(a[1][g], bf, ac[1], 0, 0, 0);
        ac[2] = __builtin_amdgcn_mfma_f32_16x16x32_bf16(a[2][g], bf, ac[2], 0, 0, 0);
        ac[3] = __builtin_amdgcn_mfma_f32_16x16x32_bf16(a[3][g], bf, ac[3], 0, 0, 0);
      }
      const int jtb = jbase + s * 64 + jt * 16;
#pragma unroll
      for (int rf = 0; rf < 4; ++rf) {
        const int itb = r0w + rf * 16;
        const bool dg = (itb == jtb);
        const bool ps = ((itb ^ B_HALF) == jtb);
        if (dg | ps) {  // wave-uniform; at most 8 of 128 tiles per wave
#pragma unroll
          for (int t = 0; t < 4; ++t) {
            float sv = ac[rf][t];
            float e = fexp2(sv * LOG2E2);
            bool self = (lm == hh * 4 + t);  // C/D map: row=hh*4+t, col=lm
            if (dg && self) e = 0.f;         // mask diagonal
            sume[rf][t] += e;
            if (ps && self) ppos[itb + hh * 4 + t] = sv * 2.0f;  // unique writer
          }
        } else {
#pragma unroll
          for (int t = 0; t < 4; ++t) sume[rf][t] += fexp2(ac[rf][t] * LOG2E2);
        }
      }
    }
  }

  // reduce partial sums across the 16 lanes (lm) sharing each row
#pragma unroll
  for (int rf = 0; rf < 4; ++rf)
#pragma unroll
    for (int t = 0; t < 4; ++t) {
      float v = sume[rf][t];
#pragma unroll
      for (int m = 1; m < 16; m <<= 1) v += __shfl_xor(v, m);
      if (lm == 0) psum[(size_t)blockIdx.y * N_TOT + r0w + rf * 16 + hh * 4 + t] = v;
    }
}

__global__ __launch_bounds__(256) void fin1_kernel(const float* __restrict__ psum,
                                                   const float* __restrict__ ppos,
                                                   float* __restrict__ partial) {
  int i = blockIdx.x * 256 + threadIdx.x;
  float se = 0.f;
#pragma unroll
  for (int s = 0; s < JSPLIT; ++s) se += psum[(size_t)s * N_TOT + i];
  float acc = logf(se) - ppos[i];
#pragma unroll
  for (int m = 32; m >= 1; m >>= 1) acc += __shfl_xor(acc, m);
  __shared__ float red[4];
  if ((threadIdx.x & 63) == 0) red[threadIdx.x >> 6] = acc;
  __syncthreads();
  if (threadIdx.x == 0) partial[blockIdx.x] = red[0] + red[1] + red[2] + red[3];
}

__global__ void fin2_kernel(const float* __restrict__ partial, float* __restrict__ out) {
  float v = (threadIdx.x < 32) ? partial[threadIdx.x] : 0.f;
#pragma unroll
  for (int m = 32; m >= 1; m >>= 1) v += __shfl_xor(v, m);
  if (threadIdx.x == 0) out[0] = v / (float)N_TOT;
}

extern "C" void kernel_launch(void* const* d_in, const int* in_sizes, int n_in,
                              void* d_out, int out_size, void* d_ws, size_t ws_size,
                              hipStream_t stream) {
  const float* z1 = (const float*)d_in[0];
  const float* z2 = (const float*)d_in[1];
  float* out = (float*)d_out;
  char* ws = (char*)d_ws;

  unsigned short* zn = (unsigned short*)ws;                 // 4 MiB
  float* psum = (float*)(ws + (size_t)N_TOT * D_DIM * 2);   // 16*8192 f32 = 512 KiB
  float* ppos = psum + (size_t)JSPLIT * N_TOT;              // 8192 f32
  float* partial = ppos + N_TOT;                            // 32 f32

  nrm_kernel<<<N_TOT / 4, 256, 0, stream>>>(z1, z2, zn);
  gram_kernel<<<dim3(N_TOT / 256, JSPLIT), 256, 0, stream>>>(zn, psum, ppos);
  fin1_kernel<<<N_TOT / 256, 256, 0, stream>>>(psum, ppos, partial);
  fin2_kernel<<<1, 64, 0, stream>>>(partial, out);
}